// Round 1
// baseline (194.273 us; speedup 1.0000x reference)
//
#include <hip/hip_runtime.h>
#include <hip/hip_bf16.h>

typedef __attribute__((ext_vector_type(8))) short short8v;   // 8 bf16 = 4 VGPRs
typedef __attribute__((ext_vector_type(4))) float f32x4;

#define N_ROWS 4096
#define M_ROWS 65536
#define DIM 64

__device__ inline unsigned short f2bf(float f) {
  unsigned u = __float_as_uint(f);
  unsigned r = (u + 0x7FFFu + ((u >> 16) & 1u)) >> 16;   // RNE
  return (unsigned short)r;
}
__device__ inline float bf2f(unsigned short s) {
  return __uint_as_float(((unsigned)s) << 16);
}

// ---------- convert f32 -> bf16, 4 elems/thread ----------
__global__ __launch_bounds__(256) void cvt_kernel(const float* __restrict__ in,
                                                  unsigned short* __restrict__ out,
                                                  int n4) {
  int i = blockIdx.x * 256 + threadIdx.x;
  if (i >= n4) return;
  float4 v = reinterpret_cast<const float4*>(in)[i];
  ushort4 o;
  o.x = f2bf(v.x); o.y = f2bf(v.y); o.z = f2bf(v.z); o.w = f2bf(v.w);
  reinterpret_cast<ushort4*>(out)[i] = o;
}

// ---------- s[n] = sum_m |u_n . sf_m|  via bf16 MFMA ----------
// block: 256 threads = 4 waves, each wave owns 64 n-rows (4x 16-row subtiles).
// grid: (16 n-blocks of 256 rows) x (64 m-chunks of 1024 rows). atomicAdd partials.
__global__ __launch_bounds__(256) void s_kernel(const unsigned short* __restrict__ u16,
                                                const unsigned short* __restrict__ sf16,
                                                float* __restrict__ S) {
  const int bn = blockIdx.x;          // 0..15
  const int bm = blockIdx.y;          // 0..63
  const int tid = threadIdx.x;
  const int wid = tid >> 6;
  const int lane = tid & 63;
  const int l15 = lane & 15;
  const int lg  = lane >> 4;          // 0..3
  const int n0 = bn * 256 + wid * 64;

  // A fragments: U rows, layout A[row=l15][k=lg*8+j (+32*kf)] -> 8 contiguous bf16
  short8v au[4][2];
#pragma unroll
  for (int st = 0; st < 4; ++st)
#pragma unroll
    for (int kf = 0; kf < 2; ++kf)
      au[st][kf] = *reinterpret_cast<const short8v*>(
          u16 + (size_t)(n0 + st * 16 + l15) * DIM + kf * 32 + lg * 8);

  f32x4 sacc[4];
#pragma unroll
  for (int st = 0; st < 4; ++st) sacc[st] = (f32x4){0.f, 0.f, 0.f, 0.f};

  const unsigned short* bptr = sf16 + (size_t)(bm * 1024 + l15) * DIM + lg * 8;

  for (int m = 0; m < 1024; m += 16) {
    short8v b0 = *reinterpret_cast<const short8v*>(bptr);
    short8v b1 = *reinterpret_cast<const short8v*>(bptr + 32);
    bptr += 16 * DIM;
#pragma unroll
    for (int st = 0; st < 4; ++st) {
      f32x4 acc = (f32x4){0.f, 0.f, 0.f, 0.f};
      acc = __builtin_amdgcn_mfma_f32_16x16x32_bf16(au[st][0], b0, acc, 0, 0, 0);
      acc = __builtin_amdgcn_mfma_f32_16x16x32_bf16(au[st][1], b1, acc, 0, 0, 0);
      sacc[st][0] += fabsf(acc[0]);
      sacc[st][1] += fabsf(acc[1]);
      sacc[st][2] += fabsf(acc[2]);
      sacc[st][3] += fabsf(acc[3]);
    }
  }

  // reduce across the 16 m-columns (lane bits 0..3)
#pragma unroll
  for (int off = 1; off < 16; off <<= 1) {
#pragma unroll
    for (int st = 0; st < 4; ++st) {
#pragma unroll
      for (int r = 0; r < 4; ++r)
        sacc[st][r] += __shfl_xor(sacc[st][r], off, 64);
    }
  }
  if (l15 == 0) {
#pragma unroll
    for (int st = 0; st < 4; ++st)
#pragma unroll
      for (int r = 0; r < 4; ++r)
        atomicAdd(&S[n0 + st * 16 + lg * 4 + r], sacc[st][r]);
  }
}

// ---------- G = SF^T SF (f32, LDS-staged bf16, 4x4 register blocking) ----------
__global__ __launch_bounds__(256) void g_kernel(const unsigned short* __restrict__ sf16,
                                                float* __restrict__ G) {
  __shared__ unsigned short tile[256][DIM];   // 32 KB
  const int tid = threadIdx.x;
  // stage: one row per thread (128 B)
  {
    const short8v* src = reinterpret_cast<const short8v*>(
        sf16 + (size_t)(blockIdx.x * 256 + tid) * DIM);
    short8v* dst = reinterpret_cast<short8v*>(&tile[tid][0]);
#pragma unroll
    for (int i = 0; i < 8; ++i) dst[i] = src[i];
  }
  __syncthreads();

  const int d1 = (tid & 15) * 4;
  const int d2 = (tid >> 4) * 4;
  float acc[4][4];
#pragma unroll
  for (int i = 0; i < 4; ++i)
#pragma unroll
    for (int j = 0; j < 4; ++j) acc[i][j] = 0.f;

#pragma unroll 4
  for (int m = 0; m < 256; ++m) {
    ushort4 a4 = *reinterpret_cast<const ushort4*>(&tile[m][d1]);
    ushort4 b4 = *reinterpret_cast<const ushort4*>(&tile[m][d2]);
    float a[4] = {bf2f(a4.x), bf2f(a4.y), bf2f(a4.z), bf2f(a4.w)};
    float b[4] = {bf2f(b4.x), bf2f(b4.y), bf2f(b4.z), bf2f(b4.w)};
#pragma unroll
    for (int i = 0; i < 4; ++i)
#pragma unroll
      for (int j = 0; j < 4; ++j) acc[i][j] += a[i] * b[j];
  }
#pragma unroll
  for (int i = 0; i < 4; ++i)
#pragma unroll
    for (int j = 0; j < 4; ++j)
      atomicAdd(&G[(d1 + i) * DIM + (d2 + j)], acc[i][j]);
}

// ---------- P = G @ W^T ----------
__global__ __launch_bounds__(64) void p_kernel(const float* __restrict__ G,
                                               const float* __restrict__ W,
                                               float* __restrict__ P) {
  const int j = blockIdx.x;     // 64
  const int d = threadIdx.x;    // 64
  float acc = 0.f;
#pragma unroll
  for (int k = 0; k < DIM; ++k) acc += G[j * DIM + k] * W[d * DIM + k];
  P[j * DIM + d] = acc;
}

// ---------- out[n,d] = u[n,d] + (u_n @ P)[d] / (max(s_n,eps)*M) + b[d] ----------
__global__ __launch_bounds__(256) void out_kernel(const float* __restrict__ u,
                                                  const float* __restrict__ P,
                                                  const float* __restrict__ S,
                                                  const float* __restrict__ bias,
                                                  float* __restrict__ out) {
  const int idx = blockIdx.x * 256 + threadIdx.x;
  const int n = idx >> 6;
  const int d = idx & 63;
  const float inv = 1.f / (fmaxf(S[n], 1e-12f) * (float)M_ROWS);
  float acc = 0.f;
#pragma unroll
  for (int j = 0; j < DIM; ++j) acc += u[n * DIM + j] * P[j * DIM + d];
  out[idx] = u[idx] + acc * inv + bias[d];
}

extern "C" void kernel_launch(void* const* d_in, const int* in_sizes, int n_in,
                              void* d_out, int out_size, void* d_ws, size_t ws_size,
                              hipStream_t stream) {
  const float* u  = (const float*)d_in[0];   // [4096,64]
  const float* sf = (const float*)d_in[1];   // [65536,64]
  const float* W  = (const float*)d_in[2];   // [64,64]
  const float* b  = (const float*)d_in[3];   // [64]
  float* out = (float*)d_out;

  char* ws = (char*)d_ws;
  unsigned short* sf16 = (unsigned short*)ws;               // 8,388,608 B
  unsigned short* u16  = (unsigned short*)(ws + 8388608);   //   524,288 B
  float* S = (float*)(ws + 8912896);                        //    16,384 B
  float* G = (float*)(ws + 8929280);                        //    16,384 B
  float* P = (float*)(ws + 8945664);                        //    16,384 B

  hipMemsetAsync(S, 0, 32768, stream);      // zeroes S and G (adjacent)
  cvt_kernel<<<dim3((M_ROWS * DIM / 4 + 255) / 256), 256, 0, stream>>>(sf, sf16, M_ROWS * DIM / 4);
  cvt_kernel<<<dim3((N_ROWS * DIM / 4 + 255) / 256), 256, 0, stream>>>(u, u16, N_ROWS * DIM / 4);
  s_kernel<<<dim3(16, 64), 256, 0, stream>>>(u16, sf16, S);
  g_kernel<<<dim3(M_ROWS / 256), 256, 0, stream>>>(sf16, G);
  p_kernel<<<dim3(64), 64, 0, stream>>>(G, W, P);
  out_kernel<<<dim3(N_ROWS * DIM / 256), 256, 0, stream>>>(u, P, S, b, out);
}

// Round 2
// 175.181 us; speedup vs baseline: 1.1090x; 1.1090x over previous
//
#include <hip/hip_runtime.h>
#include <hip/hip_bf16.h>

typedef __attribute__((ext_vector_type(8))) short short8v;   // 8 bf16 = 4 VGPRs
typedef __attribute__((ext_vector_type(4))) float f32x4;

#define N_ROWS 4096
#define M_ROWS 65536
#define DIM 64

__device__ inline unsigned short f2bf(float f) {
  unsigned u = __float_as_uint(f);
  unsigned r = (u + 0x7FFFu + ((u >> 16) & 1u)) >> 16;   // RNE
  return (unsigned short)r;
}
__device__ inline float bf2f(unsigned short s) {
  return __uint_as_float(((unsigned)s) << 16);
}

// ---------- convert f32 -> bf16, 4 elems/thread ----------
__global__ __launch_bounds__(256) void cvt_kernel(const float* __restrict__ in,
                                                  unsigned short* __restrict__ out,
                                                  int n4) {
  int i = blockIdx.x * 256 + threadIdx.x;
  if (i >= n4) return;
  float4 v = reinterpret_cast<const float4*>(in)[i];
  ushort4 o;
  o.x = f2bf(v.x); o.y = f2bf(v.y); o.z = f2bf(v.z); o.w = f2bf(v.w);
  reinterpret_cast<ushort4*>(out)[i] = o;
}

// ---------- Spart[n][bm] = sum over m-chunk bm of |u_n . sf_m| ----------
// block: 256 threads = 4 waves, each wave owns 64 n-rows (4x 16-row subtiles).
// grid: (16 n-blocks of 256 rows) x (64 m-chunks of 1024 rows).
// Register-prefetched, m unrolled x2 (32 rows / iter).
__global__ __launch_bounds__(256) void s_kernel(const unsigned short* __restrict__ u16,
                                                const unsigned short* __restrict__ sf16,
                                                float* __restrict__ Spart) {
  const int bn = blockIdx.x;          // 0..15
  const int bm = blockIdx.y;          // 0..63
  const int tid = threadIdx.x;
  const int wid = tid >> 6;
  const int lane = tid & 63;
  const int l15 = lane & 15;
  const int lg  = lane >> 4;          // 0..3
  const int n0 = bn * 256 + wid * 64;

  // A fragments: U rows. A[row=l15][k=lg*8+j (+32*kf)] -> 8 contiguous bf16
  short8v au[4][2];
#pragma unroll
  for (int st = 0; st < 4; ++st)
#pragma unroll
    for (int kf = 0; kf < 2; ++kf)
      au[st][kf] = *reinterpret_cast<const short8v*>(
          u16 + (size_t)(n0 + st * 16 + l15) * DIM + kf * 32 + lg * 8);

  f32x4 sacc[4];
#pragma unroll
  for (int st = 0; st < 4; ++st) sacc[st] = (f32x4){0.f, 0.f, 0.f, 0.f};

  const unsigned short* bptr = sf16 + (size_t)(bm * 1024 + l15) * DIM + lg * 8;

#define MFMA_STEP(X, Y)                                                        \
  {                                                                            \
    _Pragma("unroll") for (int st = 0; st < 4; ++st) {                         \
      f32x4 acc = (f32x4){0.f, 0.f, 0.f, 0.f};                                 \
      acc = __builtin_amdgcn_mfma_f32_16x16x32_bf16(au[st][0], (X), acc, 0, 0, 0); \
      acc = __builtin_amdgcn_mfma_f32_16x16x32_bf16(au[st][1], (Y), acc, 0, 0, 0); \
      sacc[st][0] += fabsf(acc[0]);                                            \
      sacc[st][1] += fabsf(acc[1]);                                            \
      sacc[st][2] += fabsf(acc[2]);                                            \
      sacc[st][3] += fabsf(acc[3]);                                            \
    }                                                                          \
  }

  short8v b0 = *reinterpret_cast<const short8v*>(bptr);
  short8v b1 = *reinterpret_cast<const short8v*>(bptr + 32);
  short8v b2 = *reinterpret_cast<const short8v*>(bptr + 16 * DIM);
  short8v b3 = *reinterpret_cast<const short8v*>(bptr + 16 * DIM + 32);

  for (int it = 0; it < 31; ++it) {
    bptr += 32 * DIM;
    short8v nb0 = *reinterpret_cast<const short8v*>(bptr);
    short8v nb1 = *reinterpret_cast<const short8v*>(bptr + 32);
    short8v nb2 = *reinterpret_cast<const short8v*>(bptr + 16 * DIM);
    short8v nb3 = *reinterpret_cast<const short8v*>(bptr + 16 * DIM + 32);
    MFMA_STEP(b0, b1);
    MFMA_STEP(b2, b3);
    b0 = nb0; b1 = nb1; b2 = nb2; b3 = nb3;
  }
  MFMA_STEP(b0, b1);
  MFMA_STEP(b2, b3);
#undef MFMA_STEP

  // reduce across the 16 m-columns (lane bits 0..3)
#pragma unroll
  for (int off = 1; off < 16; off <<= 1) {
#pragma unroll
    for (int st = 0; st < 4; ++st) {
#pragma unroll
      for (int r = 0; r < 4; ++r)
        sacc[st][r] += __shfl_xor(sacc[st][r], off, 64);
    }
  }
  if (l15 == 0) {
#pragma unroll
    for (int st = 0; st < 4; ++st)
#pragma unroll
      for (int r = 0; r < 4; ++r)
        Spart[(size_t)(n0 + st * 16 + lg * 4 + r) * 64 + bm] = sacc[st][r];
  }
}

// ---------- Gp[blk] = partial SF^T SF over 512 rows (no atomics) ----------
__global__ __launch_bounds__(256) void g_partial(const unsigned short* __restrict__ sf16,
                                                 float* __restrict__ Gp) {
  __shared__ unsigned short tile[256][DIM];   // 32 KB
  const int tid = threadIdx.x;
  const int d1 = (tid & 15) * 4;
  const int d2 = (tid >> 4) * 4;
  float acc[4][4];
#pragma unroll
  for (int i = 0; i < 4; ++i)
#pragma unroll
    for (int j = 0; j < 4; ++j) acc[i][j] = 0.f;

  for (int stg = 0; stg < 2; ++stg) {
    const short8v* src = reinterpret_cast<const short8v*>(
        sf16 + (size_t)(blockIdx.x * 512 + stg * 256 + tid) * DIM);
    short8v* dst = reinterpret_cast<short8v*>(&tile[tid][0]);
#pragma unroll
    for (int i = 0; i < 8; ++i) dst[i] = src[i];
    __syncthreads();

#pragma unroll 4
    for (int m = 0; m < 256; ++m) {
      ushort4 a4 = *reinterpret_cast<const ushort4*>(&tile[m][d1]);
      ushort4 b4 = *reinterpret_cast<const ushort4*>(&tile[m][d2]);
      float a[4] = {bf2f(a4.x), bf2f(a4.y), bf2f(a4.z), bf2f(a4.w)};
      float b[4] = {bf2f(b4.x), bf2f(b4.y), bf2f(b4.z), bf2f(b4.w)};
#pragma unroll
      for (int i = 0; i < 4; ++i)
#pragma unroll
        for (int j = 0; j < 4; ++j) acc[i][j] += a[i] * b[j];
    }
    __syncthreads();
  }
#pragma unroll
  for (int i = 0; i < 4; ++i)
#pragma unroll
    for (int j = 0; j < 4; ++j)
      Gp[(size_t)blockIdx.x * 4096 + (d1 + i) * DIM + (d2 + j)] = acc[i][j];
}

// ---------- reduce Gp -> G row j, then P[j] = G[j] @ W^T ----------
__global__ __launch_bounds__(64) void gp_reduce_p(const float* __restrict__ Gp,
                                                  const float* __restrict__ W,
                                                  float* __restrict__ P) {
  const int j = blockIdx.x;     // 64
  const int d = threadIdx.x;    // 64
  float g = 0.f;
#pragma unroll 8
  for (int p = 0; p < 128; ++p) g += Gp[(size_t)p * 4096 + j * DIM + d];
  __shared__ float row[DIM];
  row[d] = g;
  __syncthreads();
  float acc = 0.f;
#pragma unroll
  for (int k = 0; k < DIM; ++k) acc += row[k] * W[d * DIM + k];
  P[j * DIM + d] = acc;
}

// ---------- out[n,d] = u[n,d] + (u_n @ P)[d] / (max(s_n,eps)*M) + b[d] ----------
// one wave per n-row; lane = d. Spart reduced in-wave (coalesced loads).
__global__ __launch_bounds__(256) void out_kernel(const float* __restrict__ u,
                                                  const float* __restrict__ P,
                                                  const float* __restrict__ Spart,
                                                  const float* __restrict__ bias,
                                                  float* __restrict__ out) {
  __shared__ float Ps[DIM][DIM];   // 16 KB
  __shared__ float us[4][DIM];
  const int tid = threadIdx.x;
#pragma unroll
  for (int i = 0; i < 16; ++i)
    (&Ps[0][0])[tid + i * 256] = P[tid + i * 256];
  const int base = blockIdx.x * 256;
  us[tid >> 6][tid & 63] = u[base + tid];
  __syncthreads();

  const int nl = tid >> 6;
  const int d = tid & 63;
  const int n = blockIdx.x * 4 + nl;

  float sp = Spart[(size_t)n * 64 + d];
#pragma unroll
  for (int off = 1; off < 64; off <<= 1) sp += __shfl_xor(sp, off, 64);
  const float inv = 1.f / (fmaxf(sp, 1e-12f) * (float)M_ROWS);

  float acc = 0.f;
#pragma unroll
  for (int jj = 0; jj < DIM; ++jj) acc += us[nl][jj] * Ps[jj][d];
  out[base + tid] = us[nl][d] + acc * inv + bias[d];
}

extern "C" void kernel_launch(void* const* d_in, const int* in_sizes, int n_in,
                              void* d_out, int out_size, void* d_ws, size_t ws_size,
                              hipStream_t stream) {
  const float* u  = (const float*)d_in[0];   // [4096,64]
  const float* sf = (const float*)d_in[1];   // [65536,64]
  const float* W  = (const float*)d_in[2];   // [64,64]
  const float* b  = (const float*)d_in[3];   // [64]
  float* out = (float*)d_out;

  char* ws = (char*)d_ws;
  unsigned short* sf16 = (unsigned short*)ws;                // 8,388,608 B
  unsigned short* u16  = (unsigned short*)(ws + 8388608);    //   524,288 B
  float* Spart = (float*)(ws + 8912896);                     // 1,048,576 B [4096][64]
  float* Gp    = (float*)(ws + 9961472);                     // 2,097,152 B [128][4096]
  float* P     = (float*)(ws + 12058624);                    //    16,384 B

  cvt_kernel<<<dim3(M_ROWS * DIM / 4 / 256), 256, 0, stream>>>(sf, sf16, M_ROWS * DIM / 4);
  cvt_kernel<<<dim3(N_ROWS * DIM / 4 / 256), 256, 0, stream>>>(u, u16, N_ROWS * DIM / 4);
  s_kernel<<<dim3(16, 64), 256, 0, stream>>>(u16, sf16, Spart);
  g_partial<<<dim3(128), 256, 0, stream>>>(sf16, Gp);
  gp_reduce_p<<<dim3(64), 64, 0, stream>>>(Gp, W, P);
  out_kernel<<<dim3(N_ROWS * 64 / 256), 256, 0, stream>>>(u, P, Spart, b, out);
}

// Round 3
// 135.574 us; speedup vs baseline: 1.4330x; 1.2921x over previous
//
#include <hip/hip_runtime.h>
#include <hip/hip_bf16.h>

typedef __attribute__((ext_vector_type(8))) short short8v;   // 8 bf16 = 4 VGPRs
typedef __attribute__((ext_vector_type(4))) float f32x4;

#define N_ROWS 4096
#define M_ROWS 65536
#define DIM 64

#define AS1C(p) ((const __attribute__((address_space(1))) void*)(p))
#define AS3(p)  ((__attribute__((address_space(3))) void*)(p))

__device__ inline unsigned short f2bf(float f) {
  unsigned u = __float_as_uint(f);
  unsigned r = (u + 0x7FFFu + ((u >> 16) & 1u)) >> 16;   // RNE
  return (unsigned short)r;
}
__device__ inline float bf2f(unsigned short s) {
  return __uint_as_float(((unsigned)s) << 16);
}

// ---------- convert f32 -> bf16, 4 elems/thread ----------
__global__ __launch_bounds__(256) void cvt_kernel(const float* __restrict__ in,
                                                  unsigned short* __restrict__ out,
                                                  int n4) {
  int i = blockIdx.x * 256 + threadIdx.x;
  if (i >= n4) return;
  float4 v = reinterpret_cast<const float4*>(in)[i];
  ushort4 o;
  o.x = f2bf(v.x); o.y = f2bf(v.y); o.z = f2bf(v.z); o.w = f2bf(v.w);
  reinterpret_cast<ushort4*>(out)[i] = o;
}

// ---------- Spart[n][bm] = sum over m-chunk bm of |u_n . sf_m| ----------
// 4 waves/block, wave owns 64 n-rows. B staged in LDS via global_load_lds,
// double-buffered, LDS layout [kpart(8)][row(64)][8 bf16] (conflict-free b128).
// Per K-step: 64 m-rows, 32 MFMA/wave, 1 barrier.
__global__ __launch_bounds__(256) void s_kernel(const float* __restrict__ u,
                                                const unsigned short* __restrict__ sf16,
                                                float* __restrict__ Spart) {
  __shared__ unsigned short Bt[2][4096];   // 2 x 8 KB
  const int bn = blockIdx.x;          // 0..15
  const int bm = blockIdx.y;          // 0..63
  const int tid = threadIdx.x;
  const int wid = tid >> 6;
  const int lane = tid & 63;
  const int l15 = lane & 15;
  const int lg  = lane >> 4;          // 0..3
  const int n0 = bn * 256 + wid * 64;
  const int mbase = bm * 1024;

  // A fragments: convert u rows f32->bf16 in-register.
  // A[row=l15][k = kf*32 + lg*8 + j]
  short8v au[4][2];
#pragma unroll
  for (int st = 0; st < 4; ++st) {
#pragma unroll
    for (int kf = 0; kf < 2; ++kf) {
      const float* ap = u + (size_t)(n0 + st * 16 + l15) * DIM + kf * 32 + lg * 8;
      float4 f0 = *reinterpret_cast<const float4*>(ap);
      float4 f1 = *reinterpret_cast<const float4*>(ap + 4);
      short8v v;
      v[0] = (short)f2bf(f0.x); v[1] = (short)f2bf(f0.y);
      v[2] = (short)f2bf(f0.z); v[3] = (short)f2bf(f0.w);
      v[4] = (short)f2bf(f1.x); v[5] = (short)f2bf(f1.y);
      v[6] = (short)f2bf(f1.z); v[7] = (short)f2bf(f1.w);
      au[st][kf] = v;
    }
  }

  f32x4 sacc[4];
#pragma unroll
  for (int st = 0; st < 4; ++st) sacc[st] = (f32x4){0.f, 0.f, 0.f, 0.f};

  // Staging: wave w fills kparts {2w, 2w+1}. LDS dest is wave-uniform base
  // + lane*16 (linear); per-lane GLOBAL source delivers the transposed layout:
  //   LDS[kpart*1024 + lane*16] <- sf16[(mrow0 + lane)*64 + kpart*8]
#define STAGE(buf, step)                                                       \
  {                                                                            \
    _Pragma("unroll") for (int j = 0; j < 2; ++j) {                            \
      const int kp = wid * 2 + j;                                              \
      const unsigned short* g =                                                \
          sf16 + (size_t)(mbase + (step) * 64 + lane) * DIM + kp * 8;          \
      __builtin_amdgcn_global_load_lds(AS1C(g), AS3(&Bt[buf][kp * 512]), 16, 0, 0); \
    }                                                                          \
  }

  STAGE(0, 0);
  for (int s = 0; s < 16; ++s) {
    __syncthreads();                    // buf s&1 ready (vmcnt drained here)
    if (s < 15) STAGE((s + 1) & 1, s + 1);
    const unsigned short* B = &Bt[s & 1][0];
#pragma unroll
    for (int g = 0; g < 4; ++g) {       // 16-row m sub-tiles
      short8v b0 = *reinterpret_cast<const short8v*>(
          &B[(size_t)lg * 512 + (g * 16 + l15) * 8]);          // kpart = lg
      short8v b1 = *reinterpret_cast<const short8v*>(
          &B[(size_t)(4 + lg) * 512 + (g * 16 + l15) * 8]);    // kpart = 4+lg
#pragma unroll
      for (int st = 0; st < 4; ++st) {
        f32x4 acc = (f32x4){0.f, 0.f, 0.f, 0.f};
        acc = __builtin_amdgcn_mfma_f32_16x16x32_bf16(au[st][0], b0, acc, 0, 0, 0);
        acc = __builtin_amdgcn_mfma_f32_16x16x32_bf16(au[st][1], b1, acc, 0, 0, 0);
        sacc[st][0] += fabsf(acc[0]);
        sacc[st][1] += fabsf(acc[1]);
        sacc[st][2] += fabsf(acc[2]);
        sacc[st][3] += fabsf(acc[3]);
      }
    }
  }
#undef STAGE

  // reduce across the 16 m-columns (lane bits 0..3)
#pragma unroll
  for (int off = 1; off < 16; off <<= 1) {
#pragma unroll
    for (int st = 0; st < 4; ++st) {
#pragma unroll
      for (int r = 0; r < 4; ++r)
        sacc[st][r] += __shfl_xor(sacc[st][r], off, 64);
    }
  }
  if (l15 == 0) {
#pragma unroll
    for (int st = 0; st < 4; ++st)
#pragma unroll
      for (int r = 0; r < 4; ++r)
        Spart[(size_t)(n0 + st * 16 + lg * 4 + r) * 64 + bm] = sacc[st][r];
  }
}

// ---------- Gp[blk] = partial SF^T SF over 256 rows ----------
// 256 blocks x 512 threads (2 waves/SIMD). 2 phases of 128 staged rows.
__global__ __launch_bounds__(512) void g_partial(const unsigned short* __restrict__ sf16,
                                                 float* __restrict__ Gp) {
  __shared__ unsigned short tile[128][DIM];   // 16 KB
  const int tid = threadIdx.x;
  const int d1 = (tid & 15) * 4;
  const int d2 = (tid >> 4) * 2;
  float acc[4][2];
#pragma unroll
  for (int i = 0; i < 4; ++i)
#pragma unroll
    for (int j = 0; j < 2; ++j) acc[i][j] = 0.f;

  for (int ph = 0; ph < 2; ++ph) {
    {  // stage 128 rows: thread copies 32 B
      const int r = tid >> 2, q = tid & 3;
      const short8v* src = reinterpret_cast<const short8v*>(
          sf16 + (size_t)(blockIdx.x * 256 + ph * 128 + r) * DIM + q * 16);
      short8v* dst = reinterpret_cast<short8v*>(&tile[r][q * 16]);
      dst[0] = src[0];
      dst[1] = src[1];
    }
    __syncthreads();
#pragma unroll 8
    for (int m = 0; m < 128; ++m) {
      ushort4 a4 = *reinterpret_cast<const ushort4*>(&tile[m][d1]);
      ushort2 b2 = *reinterpret_cast<const ushort2*>(&tile[m][d2]);
      float a[4] = {bf2f(a4.x), bf2f(a4.y), bf2f(a4.z), bf2f(a4.w)};
      float b[2] = {bf2f(b2.x), bf2f(b2.y)};
#pragma unroll
      for (int i = 0; i < 4; ++i)
#pragma unroll
        for (int j = 0; j < 2; ++j) acc[i][j] += a[i] * b[j];
    }
    __syncthreads();
  }
#pragma unroll
  for (int i = 0; i < 4; ++i)
#pragma unroll
    for (int j = 0; j < 2; ++j)
      Gp[(size_t)blockIdx.x * 4096 + (d1 + i) * DIM + (d2 + j)] = acc[i][j];
}

// ---------- reduce Gp (256 partials) -> G row j, then P[j] = G[j] @ W^T ----------
__global__ __launch_bounds__(256) void gp_reduce_p(const float* __restrict__ Gp,
                                                   const float* __restrict__ W,
                                                   float* __restrict__ P) {
  const int j = blockIdx.x;     // 0..63
  const int d = threadIdx.x & 63;
  const int q = threadIdx.x >> 6;   // 0..3
  float g = 0.f;
#pragma unroll 8
  for (int i = 0; i < 64; ++i)
    g += Gp[(size_t)(q + 4 * i) * 4096 + j * DIM + d];
  __shared__ float part[4][DIM];
  part[q][d] = g;
  __syncthreads();
  if (q == 0) {
    float row = part[0][d] + part[1][d] + part[2][d] + part[3][d];
    part[0][d] = row;
  }
  __syncthreads();
  if (q == 0) {
    float acc = 0.f;
#pragma unroll
    for (int k = 0; k < DIM; ++k) acc += part[0][k] * W[d * DIM + k];
    P[j * DIM + d] = acc;
  }
}

// ---------- out[n,d] = u[n,d] + (u_n @ P)[d] / (max(s_n,eps)*M) + b[d] ----------
__global__ __launch_bounds__(256) void out_kernel(const float* __restrict__ u,
                                                  const float* __restrict__ P,
                                                  const float* __restrict__ Spart,
                                                  const float* __restrict__ bias,
                                                  float* __restrict__ out) {
  __shared__ float Ps[DIM][DIM];   // 16 KB
  __shared__ float us[4][DIM];
  const int tid = threadIdx.x;
#pragma unroll
  for (int i = 0; i < 16; ++i)
    (&Ps[0][0])[tid + i * 256] = P[tid + i * 256];
  const int base = blockIdx.x * 256;
  us[tid >> 6][tid & 63] = u[base + tid];
  __syncthreads();

  const int nl = tid >> 6;
  const int d = tid & 63;
  const int n = blockIdx.x * 4 + nl;

  float sp = Spart[(size_t)n * 64 + d];
#pragma unroll
  for (int off = 1; off < 64; off <<= 1) sp += __shfl_xor(sp, off, 64);
  const float inv = 1.f / (fmaxf(sp, 1e-12f) * (float)M_ROWS);

  float acc = 0.f;
#pragma unroll
  for (int jj = 0; jj < DIM; ++jj) acc += us[nl][jj] * Ps[jj][d];
  out[base + tid] = us[nl][d] + acc * inv + bias[d];
}

extern "C" void kernel_launch(void* const* d_in, const int* in_sizes, int n_in,
                              void* d_out, int out_size, void* d_ws, size_t ws_size,
                              hipStream_t stream) {
  const float* u  = (const float*)d_in[0];   // [4096,64]
  const float* sf = (const float*)d_in[1];   // [65536,64]
  const float* W  = (const float*)d_in[2];   // [64,64]
  const float* b  = (const float*)d_in[3];   // [64]
  float* out = (float*)d_out;

  char* ws = (char*)d_ws;
  unsigned short* sf16 = (unsigned short*)ws;                // 8,388,608 B
  float* Spart = (float*)(ws + 8388608);                     // 1,048,576 B [4096][64]
  float* Gp    = (float*)(ws + 9437184);                     // 4,194,304 B [256][4096]
  float* P     = (float*)(ws + 13631488);                    //    16,384 B

  cvt_kernel<<<dim3(M_ROWS * DIM / 4 / 256), 256, 0, stream>>>(sf, sf16, M_ROWS * DIM / 4);
  s_kernel<<<dim3(16, 64), 256, 0, stream>>>(u, sf16, Spart);
  g_partial<<<dim3(256), 512, 0, stream>>>(sf16, Gp);
  gp_reduce_p<<<dim3(64), 256, 0, stream>>>(Gp, W, P);
  out_kernel<<<dim3(N_ROWS * 64 / 256), 256, 0, stream>>>(u, P, Spart, b, out);
}